// Round 1
// baseline (814.013 us; speedup 1.0000x reference)
//
#include <hip/hip_runtime.h>
#include <math.h>

#define LSEQ 512
#define CS 384
#define CZ 256
#define HD 16
#define NH 12
#define NQ 4
#define NV 8
#define NALL 1152   // 192*3 + 144*2 + 288
#define SHID 3648   // NH * 304
// column offsets inside P rows
#define OFF_Q 0
#define OFF_K 192
#define OFF_V 384
#define OFF_QP 576
#define OFF_KP 720
#define OFF_VP 864

#define WC_CONST 0.2357022603955158f  // sqrt(2/(9*4))
#define WL_CONST 0.5773502691896258f  // sqrt(1/3)

// ---------------- prep: R, t, c_h ----------------
__global__ void k_prep(const float* quat, const float* trsl, const float* scale,
                       float* R, float* T, float* CH) {
  int t = threadIdx.x;
  if (t < LSEQ) {
    float w = quat[t*4+0], x = quat[t*4+1], y = quat[t*4+2], z = quat[t*4+3];
    float inv = 1.0f / sqrtf(w*w + x*x + y*y + z*z);
    w *= inv; x *= inv; y *= inv; z *= inv;
    float* r = R + t*9;
    r[0] = 1.f - 2.f*(y*y + z*z); r[1] = 2.f*(x*y - w*z);       r[2] = 2.f*(x*z + w*y);
    r[3] = 2.f*(x*y + w*z);       r[4] = 1.f - 2.f*(x*x + z*z); r[5] = 2.f*(y*z - w*x);
    r[6] = 2.f*(x*z - w*y);       r[7] = 2.f*(y*z + w*x);       r[8] = 1.f - 2.f*(x*x + y*y);
    T[t*3+0] = trsl[t*3+0]; T[t*3+1] = trsl[t*3+1]; T[t*3+2] = trsl[t*3+2];
  }
  if (t < NH) {
    float sc = scale[t];
    float sp = (sc > 20.f) ? sc : logf(1.f + expf(sc));
    CH[t] = 0.5f * WC_CONST * sp;
  }
}

// ---------------- concat weights ----------------
__global__ void k_concat(const float* Wq, const float* Wk, const float* Wv,
                         const float* Wqp, const float* Wkp, const float* Wvp,
                         float* Wcat) {
  int idx = blockIdx.x * 256 + threadIdx.x;
  if (idx >= CS * NALL) return;
  int r = idx / NALL, c = idx % NALL;
  float v;
  if (c < 192)       v = Wq [r*192 + c];
  else if (c < 384)  v = Wk [r*192 + (c-192)];
  else if (c < 576)  v = Wv [r*192 + (c-384)];
  else if (c < 720)  v = Wqp[r*144 + (c-576)];
  else if (c < 864)  v = Wkp[r*144 + (c-720)];
  else               v = Wvp[r*288 + (c-864)];
  Wcat[idx] = v;
}

// ---------------- generic f32 GEMM: C = A@B (+bias)(relu), split-K via atomics ----------------
// grid.x = ceil(N/64), grid.y = M/64, grid.z = batch*splitk
__global__ __launch_bounds__(256) void k_gemm(
    const float* A, const float* B, float* C, const float* bias,
    int M, int N, int K, int lda, int ldb, int ldc,
    long strideA, long strideB, long strideC,
    int splitk, int relu) {
  int zb = blockIdx.z;
  int batch = zb / splitk, ks = zb % splitk;
  A += (long)batch * strideA;
  B += (long)batch * strideB;
  C += (long)batch * strideC;
  int Ksub = K / splitk;
  int kbeg = ks * Ksub;

  __shared__ __align__(16) float As[16][68];
  __shared__ __align__(16) float Bs[16][68];
  int t = threadIdx.x;
  int m0 = blockIdx.y * 64, n0 = blockIdx.x * 64;
  int arow = t >> 2,  akq = (t & 3) * 4;
  int bkk  = t >> 4,  bnq = (t & 15) * 4;
  int ty = (t >> 4) * 4, tx = (t & 15) * 4;
  float acc[4][4];
  #pragma unroll
  for (int r = 0; r < 4; r++)
    #pragma unroll
    for (int c = 0; c < 4; c++) acc[r][c] = 0.f;

  for (int kb = kbeg; kb < kbeg + Ksub; kb += 16) {
    float4 av = *(const float4*)&A[(long)(m0 + arow) * lda + kb + akq];
    float4 bv;
    const float* brow = B + (long)(kb + bkk) * ldb;
    if (n0 + bnq + 3 < N) {
      bv = *(const float4*)&brow[n0 + bnq];
    } else {
      float tmp[4];
      #pragma unroll
      for (int u = 0; u < 4; u++) tmp[u] = (n0 + bnq + u < N) ? brow[n0 + bnq + u] : 0.f;
      bv = make_float4(tmp[0], tmp[1], tmp[2], tmp[3]);
    }
    __syncthreads();
    As[akq+0][arow] = av.x; As[akq+1][arow] = av.y;
    As[akq+2][arow] = av.z; As[akq+3][arow] = av.w;
    *(float4*)&Bs[bkk][bnq] = bv;
    __syncthreads();
    #pragma unroll
    for (int kk = 0; kk < 16; kk++) {
      float4 a4 = *(float4*)&As[kk][ty];
      float4 b4 = *(float4*)&Bs[kk][tx];
      acc[0][0] += a4.x*b4.x; acc[0][1] += a4.x*b4.y; acc[0][2] += a4.x*b4.z; acc[0][3] += a4.x*b4.w;
      acc[1][0] += a4.y*b4.x; acc[1][1] += a4.y*b4.y; acc[1][2] += a4.y*b4.z; acc[1][3] += a4.y*b4.w;
      acc[2][0] += a4.z*b4.x; acc[2][1] += a4.z*b4.y; acc[2][2] += a4.z*b4.z; acc[2][3] += a4.z*b4.w;
      acc[3][0] += a4.w*b4.x; acc[3][1] += a4.w*b4.y; acc[3][2] += a4.w*b4.z; acc[3][3] += a4.w*b4.w;
    }
  }

  if (splitk == 1) {
    #pragma unroll
    for (int r = 0; r < 4; r++) {
      int m = m0 + ty + r;
      #pragma unroll
      for (int c = 0; c < 4; c++) {
        int n = n0 + tx + c;
        if (n < N) {
          float v = acc[r][c] + (bias ? bias[n] : 0.f);
          if (relu) v = fmaxf(v, 0.f);
          C[(long)m * ldc + n] = v;
        }
      }
    }
  } else {
    #pragma unroll
    for (int r = 0; r < 4; r++) {
      int m = m0 + ty + r;
      #pragma unroll
      for (int c = 0; c < 4; c++) {
        int n = n0 + tx + c;
        if (n < N) {
          float v = acc[r][c] + ((ks == 0 && bias) ? bias[n] : 0.f);
          atomicAdd(&C[(long)m * ldc + n], v);
        }
      }
    }
  }
}

// ---------------- rigid transforms: QPP, KPP, VB=[v|vpp] ----------------
__global__ void k_trans(const float* P, const float* R, const float* T,
                        float* QPP, float* KPP, float* VB) {
  int idx = blockIdx.x * 256 + threadIdx.x;
  if (idx >= LSEQ * NH) return;
  int l = idx / NH, h = idx % NH;
  const float* r = R + l*9;
  float t0 = T[l*3], t1 = T[l*3+1], t2 = T[l*3+2];
  const float* prow = P + (long)l * NALL;
  #pragma unroll
  for (int pq = 0; pq < NQ; pq++) {
    const float* x = prow + OFF_QP + h*12 + pq*3;
    float a = x[0], b = x[1], c = x[2];
    float* o = QPP + l*144 + h*12 + pq*3;
    o[0] = r[0]*a + r[1]*b + r[2]*c + t0;
    o[1] = r[3]*a + r[4]*b + r[5]*c + t1;
    o[2] = r[6]*a + r[7]*b + r[8]*c + t2;
  }
  #pragma unroll
  for (int pq = 0; pq < NQ; pq++) {
    const float* x = prow + OFF_KP + h*12 + pq*3;
    float a = x[0], b = x[1], c = x[2];
    float* o = KPP + l*144 + h*12 + pq*3;
    o[0] = r[0]*a + r[1]*b + r[2]*c + t0;
    o[1] = r[3]*a + r[4]*b + r[5]*c + t1;
    o[2] = r[6]*a + r[7]*b + r[8]*c + t2;
  }
  float* vb = VB + ((long)(h * LSEQ + l)) * 40;
  #pragma unroll
  for (int d = 0; d < 16; d++) vb[d] = prow[OFF_V + h*16 + d];
  #pragma unroll
  for (int pv = 0; pv < NV; pv++) {
    const float* x = prow + OFF_VP + h*24 + pv*3;
    float a = x[0], b = x[1], c = x[2];
    vb[16 + 3*pv + 0] = r[0]*a + r[1]*b + r[2]*c + t0;
    vb[16 + 3*pv + 1] = r[3]*a + r[4]*b + r[5]*c + t1;
    vb[16 + 3*pv + 2] = r[6]*a + r[7]*b + r[8]*c + t2;
  }
}

// ---------------- b = z @ Wb, stored [i][h][j] ----------------
// grid: 512*16 blocks (i, j-tile of 32), 256 threads
__global__ __launch_bounds__(256) void k_bias(const float* zin, const float* Wb, float* Bb) {
  __shared__ __align__(16) float zl[32][260];
  __shared__ __align__(16) float wb[NH][256];
  int i  = blockIdx.x >> 4;
  int j0 = (blockIdx.x & 15) * 32;
  int t = threadIdx.x;
  for (int idx = t; idx < NH * 256; idx += 256)
    wb[idx >> 8][idx & 255] = Wb[(idx & 255) * NH + (idx >> 8)];
  const float* zsrc = zin + ((long)i * LSEQ + j0) * CZ;
  #pragma unroll
  for (int k = 0; k < 8; k++) {
    int idx = k * 256 + t;          // 2048 float4s = 32 rows x 64
    int row = idx >> 6, col = (idx & 63) << 2;
    *(float4*)&zl[row][col] = *(const float4*)&zsrc[(long)row * CZ + col];
  }
  __syncthreads();
  int jl = t >> 3, q = t & 7;       // 32 j-rows x 8 c-slices
  float acc[NH];
  #pragma unroll
  for (int h = 0; h < NH; h++) acc[h] = 0.f;
  for (int cc = q * 32; cc < q * 32 + 32; cc += 4) {
    float4 zv = *(float4*)&zl[jl][cc];
    #pragma unroll
    for (int h = 0; h < NH; h++) {
      float4 wv = *(float4*)&wb[h][cc];
      acc[h] += zv.x*wv.x + zv.y*wv.y + zv.z*wv.z + zv.w*wv.w;
    }
  }
  #pragma unroll
  for (int h = 0; h < NH; h++) {
    acc[h] += __shfl_xor(acc[h], 1);
    acc[h] += __shfl_xor(acc[h], 2);
    acc[h] += __shfl_xor(acc[h], 4);
  }
  if (q == 0) {
    #pragma unroll
    for (int h = 0; h < NH; h++)
      Bb[((long)i * NH + h) * LSEQ + j0 + jl] = acc[h];
  }
}

// ---------------- attention logits + softmax; a overwrites Bb in place ----------------
// grid 512 (i), block 512 (j)
__global__ __launch_bounds__(512) void k_attn(const float* P, const float* QPP,
    const float* KPP, const float* Bb, const float* CH, float* Aa) {
  int i = blockIdx.x, t = threadIdx.x;
  __shared__ __align__(16) float sq[192];
  __shared__ __align__(16) float sp[144];
  __shared__ float red[8];
  __shared__ float bc[2];
  if (t < 192) sq[t] = P[(long)i * NALL + t];
  if (t < 144) sp[t] = QPP[i * 144 + t];
  __syncthreads();
  int j = t;
  for (int h = 0; h < NH; h++) {
    const float* krow = P + (long)j * NALL + OFF_K + h * HD;
    float4 q0 = *(float4*)&sq[h*16+0],  q1 = *(float4*)&sq[h*16+4];
    float4 q2 = *(float4*)&sq[h*16+8],  q3 = *(float4*)&sq[h*16+12];
    float4 k0 = *(const float4*)&krow[0],  k1 = *(const float4*)&krow[4];
    float4 k2 = *(const float4*)&krow[8],  k3 = *(const float4*)&krow[12];
    float dot = q0.x*k0.x + q0.y*k0.y + q0.z*k0.z + q0.w*k0.w
              + q1.x*k1.x + q1.y*k1.y + q1.z*k1.z + q1.w*k1.w
              + q2.x*k2.x + q2.y*k2.y + q2.z*k2.z + q2.w*k2.w
              + q3.x*k3.x + q3.y*k3.y + q3.z*k3.z + q3.w*k3.w;
    const float* kpp = KPP + j * 144 + h * 12;
    float4 p0 = *(float4*)&sp[h*12+0], p1 = *(float4*)&sp[h*12+4], p2 = *(float4*)&sp[h*12+8];
    float4 c0 = *(const float4*)&kpp[0], c1 = *(const float4*)&kpp[4], c2 = *(const float4*)&kpp[8];
    float d;
    float d2 = 0.f;
    d = p0.x-c0.x; d2 += d*d;  d = p0.y-c0.y; d2 += d*d;
    d = p0.z-c0.z; d2 += d*d;  d = p0.w-c0.w; d2 += d*d;
    d = p1.x-c1.x; d2 += d*d;  d = p1.y-c1.y; d2 += d*d;
    d = p1.z-c1.z; d2 += d*d;  d = p1.w-c1.w; d2 += d*d;
    d = p2.x-c2.x; d2 += d*d;  d = p2.y-c2.y; d2 += d*d;
    d = p2.z-c2.z; d2 += d*d;  d = p2.w-c2.w; d2 += d*d;
    float bb = Bb[((long)i * NH + h) * LSEQ + j];
    float logit = WL_CONST * (dot * 0.25f + bb - CH[h] * d2);

    float m = logit;
    #pragma unroll
    for (int off = 32; off >= 1; off >>= 1) m = fmaxf(m, __shfl_xor(m, off));
    if ((t & 63) == 0) red[t >> 6] = m;
    __syncthreads();
    if (t == 0) {
      float mm = red[0];
      #pragma unroll
      for (int u = 1; u < 8; u++) mm = fmaxf(mm, red[u]);
      bc[0] = mm;
    }
    __syncthreads();
    float e = expf(logit - bc[0]);
    float s = e;
    #pragma unroll
    for (int off = 32; off >= 1; off >>= 1) s += __shfl_xor(s, off);
    if ((t & 63) == 0) red[t >> 6] = s;
    __syncthreads();
    if (t == 0) {
      float ss = 0.f;
      #pragma unroll
      for (int u = 0; u < 8; u++) ss += red[u];
      bc[1] = ss;
    }
    __syncthreads();
    Aa[((long)i * NH + h) * LSEQ + j] = e / bc[1];
    __syncthreads();
  }
}

// ---------------- op = a . z, written straight into shid ----------------
// grid 512 (i), block 256 (c)
__global__ __launch_bounds__(256) void k_op(const float* zin, const float* Aa, float* SH) {
  __shared__ __align__(16) float al[NH][512];
  int i = blockIdx.x, t = threadIdx.x;
  const float* asrc = Aa + (long)i * NH * LSEQ;
  for (int idx = t; idx < NH * LSEQ; idx += 256) al[idx >> 9][idx & 511] = asrc[idx];
  __syncthreads();
  const float* zrow = zin + (long)i * LSEQ * CZ + t;
  float acc[NH];
  #pragma unroll
  for (int h = 0; h < NH; h++) acc[h] = 0.f;
  for (int j = 0; j < LSEQ; j += 4) {
    float z0 = zrow[(long)(j+0) * CZ];
    float z1 = zrow[(long)(j+1) * CZ];
    float z2 = zrow[(long)(j+2) * CZ];
    float z3 = zrow[(long)(j+3) * CZ];
    #pragma unroll
    for (int h = 0; h < NH; h++) {
      float4 a4 = *(float4*)&al[h][j];
      acc[h] += a4.x*z0 + a4.y*z1 + a4.z*z2 + a4.w*z3;
    }
  }
  float* sh = SH + (long)i * SHID + t;
  #pragma unroll
  for (int h = 0; h < NH; h++) sh[h * 304] = acc[h];
}

// ---------------- ovp inverse transform + norm + shid fill ----------------
__global__ void k_ovp(const float* OVT, const float* R, const float* T, float* SH) {
  int idx = blockIdx.x * 256 + threadIdx.x;
  if (idx >= LSEQ * NH) return;
  int l = idx / NH, h = idx % NH;
  const float* o = OVT + ((long)(h * LSEQ + l)) * 40;
  float* sh = SH + (long)l * SHID + h * 304;
  #pragma unroll
  for (int d = 0; d < 16; d++) sh[256 + d] = o[d];
  const float* r = R + l*9;
  float t0 = T[l*3], t1 = T[l*3+1], t2 = T[l*3+2];
  #pragma unroll
  for (int v = 0; v < NV; v++) {
    float a = o[16+3*v+0] - t0, b = o[16+3*v+1] - t1, c = o[16+3*v+2] - t2;
    float x = r[0]*a + r[3]*b + r[6]*c;   // R^T
    float y = r[1]*a + r[4]*b + r[7]*c;
    float zz= r[2]*a + r[5]*b + r[8]*c;
    sh[272 + 3*v + 0] = x;
    sh[272 + 3*v + 1] = y;
    sh[272 + 3*v + 2] = zz;
    sh[296 + v] = sqrtf(x*x + y*y + zz*zz);
  }
}

// ---------------- layernorm: out = LN(res + y) * g + b ----------------
__global__ __launch_bounds__(384) void k_ln(const float* res, const float* y,
                                            const float* g, const float* b, float* out) {
  int l = blockIdx.x, t = threadIdx.x;
  __shared__ float red1[6], red2[6];
  __shared__ float mv[2];
  float x = res[(long)l * CS + t] + y[(long)l * CS + t];
  float s = x, s2 = x * x;
  #pragma unroll
  for (int off = 32; off >= 1; off >>= 1) { s += __shfl_xor(s, off); s2 += __shfl_xor(s2, off); }
  if ((t & 63) == 0) { red1[t >> 6] = s; red2[t >> 6] = s2; }
  __syncthreads();
  if (t == 0) {
    float ss = 0.f, ss2 = 0.f;
    #pragma unroll
    for (int u = 0; u < 6; u++) { ss += red1[u]; ss2 += red2[u]; }
    float m = ss / CS;
    float var = ss2 / CS - m * m;
    mv[0] = m; mv[1] = 1.0f / sqrtf(var + 1e-5f);
  }
  __syncthreads();
  out[(long)l * CS + t] = (x - mv[0]) * mv[1] * g[t] + b[t];
}

// ---------------- launcher ----------------
extern "C" void kernel_launch(void* const* d_in, const int* in_sizes, int n_in,
                              void* d_out, int out_size, void* d_ws, size_t ws_size,
                              hipStream_t stream) {
  const float* s    = (const float*)d_in[0];
  const float* z    = (const float*)d_in[1];
  const float* quat = (const float*)d_in[2];
  const float* trsl = (const float*)d_in[3];
  const float* Wq   = (const float*)d_in[4];
  const float* Wk   = (const float*)d_in[5];
  const float* Wv   = (const float*)d_in[6];
  const float* Wqp  = (const float*)d_in[7];
  const float* Wkp  = (const float*)d_in[8];
  const float* Wvp  = (const float*)d_in[9];
  const float* Wb   = (const float*)d_in[10];
  const float* Ws   = (const float*)d_in[11];
  const float* bs   = (const float*)d_in[12];
  const float* scale= (const float*)d_in[13];
  const float* g1   = (const float*)d_in[14];
  const float* b1   = (const float*)d_in[15];
  const float* Wm1  = (const float*)d_in[16];
  const float* bm1  = (const float*)d_in[17];
  const float* Wm2  = (const float*)d_in[18];
  const float* bm2  = (const float*)d_in[19];
  const float* Wm3  = (const float*)d_in[20];
  const float* bm3  = (const float*)d_in[21];
  const float* g2   = (const float*)d_in[22];
  const float* b2   = (const float*)d_in[23];
  float* out = (float*)d_out;

  float* p = (float*)d_ws;
  float* R    = p; p += 512*9;
  float* T    = p; p += 512*3;
  float* CH   = p; p += 16;
  float* Wcat = p; p += (long)CS*NALL;
  float* P    = p; p += (long)LSEQ*NALL;
  float* QPP  = p; p += LSEQ*144;
  float* KPP  = p; p += LSEQ*144;
  float* VB   = p; p += (long)NH*LSEQ*40;
  float* Bb   = p; p += (long)LSEQ*NH*LSEQ;   // also holds a (in-place softmax)
  float* OVT  = p; p += (long)NH*LSEQ*40;
  float* SH   = p; p += (long)LSEQ*SHID;
  float* T1   = p; p += LSEQ*CS;
  float* S1   = p; p += LSEQ*CS;
  float* H1   = p; p += LSEQ*CS;
  float* H2   = p; p += LSEQ*CS;
  float* H3   = p; p += LSEQ*CS;
  float* Aa   = Bb;

  k_prep<<<1, 512, 0, stream>>>(quat, trsl, scale, R, T, CH);
  k_concat<<<(CS*NALL + 255)/256, 256, 0, stream>>>(Wq, Wk, Wv, Wqp, Wkp, Wvp, Wcat);
  // P = s @ Wcat
  k_gemm<<<dim3(NALL/64, LSEQ/64, 1), 256, 0, stream>>>(
      s, Wcat, P, nullptr, LSEQ, NALL, CS, CS, NALL, NALL, 0, 0, 0, 1, 0);
  k_trans<<<(LSEQ*NH + 255)/256, 256, 0, stream>>>(P, R, T, QPP, KPP, VB);
  k_bias<<<LSEQ*16, 256, 0, stream>>>(z, Wb, Bb);
  k_attn<<<LSEQ, 512, 0, stream>>>(P, QPP, KPP, Bb, CH, Aa);
  k_op<<<LSEQ, 256, 0, stream>>>(z, Aa, SH);
  // OVT[h] = a[:,h,:] @ VB[h]   (batched over h)
  k_gemm<<<dim3(1, LSEQ/64, NH), 256, 0, stream>>>(
      Aa, VB, OVT, nullptr, LSEQ, 40, LSEQ,
      NH*LSEQ, 40, 40, 512, (long)LSEQ*40, (long)LSEQ*40, 1, 0);
  k_ovp<<<(LSEQ*NH + 255)/256, 256, 0, stream>>>(OVT, R, T, SH);
  // T1 = SH @ Ws + bs   (split-K=6, atomic accumulate)
  hipMemsetAsync(T1, 0, (size_t)LSEQ*CS*sizeof(float), stream);
  k_gemm<<<dim3(CS/64, LSEQ/64, 6), 256, 0, stream>>>(
      SH, Ws, T1, bs, LSEQ, CS, SHID, SHID, CS, CS, 0, 0, 0, 6, 0);
  k_ln<<<LSEQ, CS, 0, stream>>>(s, T1, g1, b1, S1);
  k_gemm<<<dim3(CS/64, LSEQ/64, 1), 256, 0, stream>>>(
      S1, Wm1, H1, bm1, LSEQ, CS, CS, CS, CS, CS, 0, 0, 0, 1, 1);
  k_gemm<<<dim3(CS/64, LSEQ/64, 1), 256, 0, stream>>>(
      H1, Wm2, H2, bm2, LSEQ, CS, CS, CS, CS, CS, 0, 0, 0, 1, 1);
  k_gemm<<<dim3(CS/64, LSEQ/64, 1), 256, 0, stream>>>(
      H2, Wm3, H3, bm3, LSEQ, CS, CS, CS, CS, CS, 0, 0, 0, 1, 0);
  k_ln<<<LSEQ, CS, 0, stream>>>(S1, H3, g2, b2, out);
}